// Round 2
// baseline (274.092 us; speedup 1.0000x reference)
//
#include <hip/hip_runtime.h>
#include <hip/hip_bf16.h>
#include <stdint.h>

// B=32768, D=1024, T=8, O=128, DEPTH=6 -> 512 padded node cols (8 trees x 64)
#define KDIM 1024
#define TSTR 72            // tree stride in s/mu LDS tile (shorts): 144 B
#define RSTR 576           // row stride = 8*TSTR (shorts)

typedef __attribute__((ext_vector_type(4))) float f32x4;
typedef __attribute__((ext_vector_type(8))) short bf16x8;

// ws layout: wb [32 ks][32 cb][64 lane][8] bf16 = 1 MiB @0 ; lb [16 kq][8 ob][64 lane][8] bf16 = 128 KiB @1 MiB
#define WS_LB_OFF ((size_t)1 << 20)

__device__ __forceinline__ unsigned short f2bf_rne(float f) {
    unsigned u = __float_as_uint(f);
    u = (u + 0x7fffu + ((u >> 16) & 1u)) >> 16;
    return (unsigned short)u;
}

__device__ __forceinline__ unsigned int pack2_bf16(float a, float b) {
    __hip_bfloat162 h = __float22bfloat162_rn(make_float2(a, b));
    union { __hip_bfloat162 h; unsigned int u; } cv;
    cv.h = h;
    return cv.u;   // a in low 16 bits, b in high
}

// extract bf16 element i (0..63) from 8 packed uint4s; i is constant after unroll
__device__ __forceinline__ float gs_get(const uint4* q, int i) {
    uint4 v = q[i >> 3];
    int c = (i >> 1) & 3;
    unsigned w = (c == 0) ? v.x : (c == 1) ? v.y : (c == 2) ? v.z : v.w;
    return __uint_as_float((i & 1) ? (w & 0xffff0000u) : (w << 16));
}

// 8 fp32 (two f32x4, k-consecutive) -> bf16x8 fragment
__device__ __forceinline__ bf16x8 cvt8(f32x4 lo, f32x4 hi) {
    union { uint4 u; bf16x8 v; } cv;
    cv.u.x = pack2_bf16(lo[0], lo[1]);
    cv.u.y = pack2_bf16(lo[2], lo[3]);
    cv.u.z = pack2_bf16(hi[0], hi[1]);
    cv.u.w = pack2_bf16(hi[2], hi[3]);
    return cv.v;
}

// ---- prep: node weights -> bf16 fragment-linear: wb[((ks*32+cb)*64+lane)*8+e]
//      = W[k = ks*32 + (lane>>4)*8 + e][col = cb*16 + (lane&15)]
// fused reads af as one coalesced 16B/lane global load per fragment (L2-hot, 1 MiB).
__global__ void prep_w(const float* __restrict__ nw, unsigned short* __restrict__ wb) {
    int idx = blockIdx.x * 256 + threadIdx.x;       // 524288 total
    int e    = idx & 7;
    int lane = (idx >> 3) & 63;
    int cb   = (idx >> 9) & 31;
    int ks   = idx >> 14;
    int col = cb * 16 + (lane & 15);
    int k   = ks * 32 + (lane >> 4) * 8 + e;
    int t = col >> 6, i = col & 63;
    float v = (i < 63) ? nw[(t * KDIM + k) * 63 + i] : 0.0f;
    wb[idx] = f2bf_rne(v);
}

// ---- prep: leaf weights -> bf16 fragment-linear: lb[((kq*8+obk)*64+lane)*8+e]
//      = L[c = kq*32 + (lane>>4)*8 + e][o = obk*16 + (lane&15)]
__global__ void prep_l(const float* __restrict__ lw, unsigned short* __restrict__ lb) {
    int idx = blockIdx.x * 256 + threadIdx.x;       // 65536 total
    int e    = idx & 7;
    int lane = (idx >> 3) & 63;
    int obk  = (idx >> 9) & 7;
    int kq   = idx >> 12;
    int o = obk * 16 + (lane & 15);
    int c = kq * 32 + (lane >> 4) * 8 + e;
    int t = c >> 6, l = c & 63;
    lb[idx] = f2bf_rne(lw[(t * 128 + o) * 64 + l]);
}

// ---- fused: s = smooth_step(x@W) [MFMA] -> tree scan -> out = mu@L [MFMA] ----
// block: 64 rows x 512 cols, K=1024. 4 waves, each 64 rows x 128 cols.
// k-loop is BARRIER-FREE: x fragments loaded per-lane from global fp32 (block-
// exclusive rows, L1/L2-absorbed 4x wave reuse), W fragments from the L2-hot
// fragment-linear wb. LDS holds only the 36,864 B s/mu tile for the phases.
__launch_bounds__(256, 2)
__global__ void fused(const float* __restrict__ x, const unsigned short* __restrict__ wb,
                      const unsigned short* __restrict__ lb, float* __restrict__ out) {
    __shared__ __align__(16) unsigned short st[32 * RSTR];   // 36,864 B

    const int tid  = threadIdx.x;
    const int wave = tid >> 6, lane = tid & 63;
    const int quad = lane >> 4, l16 = lane & 15;
    const int mb   = blockIdx.x;           // 512 blocks x 64 rows

    f32x4 acc[8][4];                       // [ct: col tile][rt: row tile]
    const f32x4 z4 = {0.f, 0.f, 0.f, 0.f};
    #pragma unroll
    for (int a = 0; a < 8; ++a)
        #pragma unroll
        for (int b = 0; b < 4; ++b) acc[a][b] = z4;

    // per-rt row base pointers (fixed across ks)
    const float* xr0 = x + (size_t)(mb * 64 + 0 * 16 + l16) * KDIM + quad * 8;
    const float* xr1 = x + (size_t)(mb * 64 + 1 * 16 + l16) * KDIM + quad * 8;
    const float* xr2 = x + (size_t)(mb * 64 + 2 * 16 + l16) * KDIM + quad * 8;
    const float* xr3 = x + (size_t)(mb * 64 + 3 * 16 + l16) * KDIM + quad * 8;
    const unsigned short* wb0 = wb + (size_t)(wave * 8 * 64 + lane) * 8;

    for (int ks = 0; ks < 32; ++ks) {
        bf16x8 af[8], bf[4];
        {
            f32x4 lo, hi;
            lo = *(const f32x4*)(xr0 + ks * 32); hi = *(const f32x4*)(xr0 + ks * 32 + 4);
            bf[0] = cvt8(lo, hi);
            lo = *(const f32x4*)(xr1 + ks * 32); hi = *(const f32x4*)(xr1 + ks * 32 + 4);
            bf[1] = cvt8(lo, hi);
            lo = *(const f32x4*)(xr2 + ks * 32); hi = *(const f32x4*)(xr2 + ks * 32 + 4);
            bf[2] = cvt8(lo, hi);
            lo = *(const f32x4*)(xr3 + ks * 32); hi = *(const f32x4*)(xr3 + ks * 32 + 4);
            bf[3] = cvt8(lo, hi);
        }
        const unsigned short* wbase = wb0 + (size_t)ks * 16384;   // [ks][cb=wave*8..][lane][8]
        #pragma unroll
        for (int ct = 0; ct < 8; ++ct)
            af[ct] = *(const bf16x8*)(wbase + ct * 512);
        #pragma unroll
        for (int ct = 0; ct < 8; ++ct)
            #pragma unroll
            for (int rt = 0; rt < 4; ++rt)
                acc[ct][rt] = __builtin_amdgcn_mfma_f32_16x16x32_bf16(af[ct], bf[rt], acc[ct][rt], 0, 0, 0);
    }

    // two 32-row phases: epilogue(s->LDS) -> scan(mu in place) -> GEMM2 -> out
    #pragma unroll
    for (int p = 0; p < 2; ++p) {
        __syncthreads();   // p=0: no-op hazard-wise; p=1: gemm2 p=0 readers done
        // epilogue: smooth_step, write s bf16 into st (tree-strided layout)
        #pragma unroll
        for (int rt2 = 0; rt2 < 2; ++rt2) {
            int rowl = rt2 * 16 + l16;                    // phase-local row 0..31
            #pragma unroll
            for (int ct = 0; ct < 8; ++ct) {
                int colb = wave * 128 + ct * 16 + quad * 4;
                f32x4 a = acc[ct][p * 2 + rt2];
                float s0[4];
                #pragma unroll
                for (int j = 0; j < 4; ++j) {
                    float u = a[j];
                    u = fminf(fmaxf(u, -0.5f), 0.5f);     // cubic(+-.5) = 1/0 exactly
                    s0[j] = u * (1.5f - 2.0f * u * u) + 0.5f;
                }
                uint2 pk;
                pk.x = pack2_bf16(s0[0], s0[1]);
                pk.y = pack2_bf16(s0[2], s0[3]);
                *(uint2*)&st[rowl * RSTR + (colb >> 6) * TSTR + (colb & 63)] = pk;
            }
        }
        __syncthreads();
        // scan: one (row, tree) per thread, in place s -> mu
        {
            int r = tid >> 3, t = tid & 7;
            unsigned short* base = &st[r * RSTR + t * TSTR];
            uint4 q[8];
            #pragma unroll
            for (int c = 0; c < 8; ++c) q[c] = *(const uint4*)(base + c * 8);
            float mu[32];
            mu[0] = 1.0f;
            int start = 0;
            #pragma unroll
            for (int lvl = 0; lvl < 5; ++lvl) {           // levels 0..4 in-register
                int width = 1 << lvl;
                #pragma unroll
                for (int j = width - 1; j >= 0; --j) {
                    float m = mu[j], s_ = gs_get(q, start + j);
                    mu[2 * j + 1] = m * (1.0f - s_);
                    mu[2 * j]     = m * s_;
                }
                start += width;
            }
            #pragma unroll
            for (int c = 0; c < 8; ++c) {                 // level 5 fused with pack+store
                unsigned pk2[4];
                #pragma unroll
                for (int e = 0; e < 4; ++e) {
                    int j = c * 4 + e;
                    float m = mu[j], s_ = gs_get(q, 31 + j);
                    pk2[e] = pack2_bf16(m * s_, m * (1.0f - s_));
                }
                uint4 v; v.x = pk2[0]; v.y = pk2[1]; v.z = pk2[2]; v.w = pk2[3];
                *(uint4*)(base + c * 8) = v;
            }
        }
        __syncthreads();
        // GEMM2: A = leaf (global fragment-linear, L2-hot), B = mu (LDS)
        {
            int rtile = wave & 1, obw = wave >> 1;
            f32x4 a2[4];
            a2[0] = z4; a2[1] = z4; a2[2] = z4; a2[3] = z4;
            #pragma unroll
            for (int kq = 0; kq < 16; ++kq) {
                int c0 = kq * 32 + quad * 8;
                bf16x8 bmu = *(const bf16x8*)&st[(rtile * 16 + l16) * RSTR + (c0 >> 6) * TSTR + (c0 & 63)];
                const unsigned short* lbase = lb + ((size_t)((kq * 8 + obw * 4) * 64 + lane)) * 8;
                #pragma unroll
                for (int ct = 0; ct < 4; ++ct) {
                    bf16x8 alf = *(const bf16x8*)(lbase + ct * 512);
                    a2[ct] = __builtin_amdgcn_mfma_f32_16x16x32_bf16(alf, bmu, a2[ct], 0, 0, 0);
                }
            }
            #pragma unroll
            for (int ct = 0; ct < 4; ++ct) {
                int rowg = mb * 64 + p * 32 + rtile * 16 + l16;
                int og = obw * 64 + ct * 16 + quad * 4;
                *(f32x4*)(out + (size_t)rowg * 128 + og) = a2[ct];
            }
        }
    }
}

extern "C" void kernel_launch(void* const* d_in, const int* in_sizes, int n_in,
                              void* d_out, int out_size, void* d_ws, size_t ws_size,
                              hipStream_t stream) {
    const float* x  = (const float*)d_in[0];
    const float* nw = (const float*)d_in[1];
    const float* lw = (const float*)d_in[2];
    float* out = (float*)d_out;

    unsigned short* wb = (unsigned short*)d_ws;
    unsigned short* lb = (unsigned short*)((char*)d_ws + WS_LB_OFF);

    prep_w<<<2048, 256, 0, stream>>>(nw, wb);
    prep_l<<<256, 256, 0, stream>>>(lw, lb);
    fused<<<512, 256, 0, stream>>>(x, wb, lb, out);
}

// Round 4
// 250.382 us; speedup vs baseline: 1.0947x; 1.0947x over previous
//
#include <hip/hip_runtime.h>
#include <hip/hip_bf16.h>
#include <stdint.h>

// B=32768, D=1024, T=8, O=128, DEPTH=6 -> 512 padded node cols (8 trees x 64)
#define KDIM 1024
#define XSTR2 520          // x LDS row stride (shorts): 1040 B = 65 x 16B -> (row+quad)%8 slot spread, 2 lanes/bank (free)
#define TSTR 72            // tree stride in st (shorts) — R0's proven layout
#define RSTR 576           // st row stride (shorts) = 8*TSTR

typedef __attribute__((ext_vector_type(4))) float f32x4;
typedef __attribute__((ext_vector_type(8))) short bf16x8;

// ws: wb [32 ks][32 cb][64 lane][8] bf16 = 1 MiB @0 ; lb [16 kq][8 obk][64 lane][8] bf16 @1 MiB
#define WS_LB_OFF ((size_t)1 << 20)

__device__ __forceinline__ unsigned short f2bf_rne(float f) {
    unsigned u = __float_as_uint(f);
    u = (u + 0x7fffu + ((u >> 16) & 1u)) >> 16;
    return (unsigned short)u;
}

__device__ __forceinline__ unsigned int pack2_bf16(float a, float b) {
    __hip_bfloat162 h = __float22bfloat162_rn(make_float2(a, b));
    union { __hip_bfloat162 h; unsigned int u; } cv;
    cv.h = h;
    return cv.u;   // a low 16, b high
}

__device__ __forceinline__ float gs_get(const uint4* q, int i) {
    uint4 v = q[i >> 3];
    int c = (i >> 1) & 3;
    unsigned w = (c == 0) ? v.x : (c == 1) ? v.y : (c == 2) ? v.z : v.w;
    return __uint_as_float((i & 1) ? (w & 0xffff0000u) : (w << 16));
}

// ---- prep: node weights -> bf16 fragment-linear: wb[((ks*32+cb)*64+lane)*8+e]
//      = W[k = ks*32 + (lane>>4)*8 + e][col = cb*16 + (lane&15)]   (proven R2)
__global__ void prep_w(const float* __restrict__ nw, unsigned short* __restrict__ wb) {
    int idx = blockIdx.x * 256 + threadIdx.x;       // 524288 total
    int e    = idx & 7;
    int lane = (idx >> 3) & 63;
    int cb   = (idx >> 9) & 31;
    int ks   = idx >> 14;
    int col = cb * 16 + (lane & 15);
    int k   = ks * 32 + (lane >> 4) * 8 + e;
    int t = col >> 6, i = col & 63;
    float v = (i < 63) ? nw[(t * KDIM + k) * 63 + i] : 0.0f;
    wb[idx] = f2bf_rne(v);
}

// ---- prep: leaf weights -> bf16 fragment-linear: lb[((kq*8+obk)*64+lane)*8+e]
//      = L[c = kq*32 + (lane>>4)*8 + e][o = obk*16 + (lane&15)]    (proven R2)
__global__ void prep_l(const float* __restrict__ lw, unsigned short* __restrict__ lb) {
    int idx = blockIdx.x * 256 + threadIdx.x;       // 65536 total
    int e    = idx & 7;
    int lane = (idx >> 3) & 63;
    int obk  = (idx >> 9) & 7;
    int kq   = idx >> 12;
    int o = obk * 16 + (lane & 15);
    int c = kq * 32 + (lane >> 4) * 8 + e;
    int t = c >> 6, l = c & 63;
    lb[idx] = f2bf_rne(lw[(t * 128 + o) * 64 + l]);
}

// ---- fused: block = 1024 thr (16 waves), tile 64 rows x 512 cols, acc[2][4].
// x staged to LDS bf16 in TWO 512-k halves with R0's proven barrier-stage-barrier
// pattern (3 barriers total in GEMM1, none in the inner loop). W direct global.
__launch_bounds__(1024, 4)
__global__ void fused(const float* __restrict__ x, const unsigned short* __restrict__ wb,
                      const unsigned short* __restrict__ lb, float* __restrict__ out) {
    __shared__ __align__(16) unsigned short xs[64 * XSTR2];   // 66,560 B
    __shared__ __align__(16) unsigned short st[32 * RSTR];    // 36,864 B

    const int tid  = threadIdx.x;
    const int wave = tid >> 6, lane = tid & 63;
    const int quad = lane >> 4, l16 = lane & 15;
    const int mb   = blockIdx.x;           // 512 blocks x 64 rows

    f32x4 acc[2][4];                       // [ct][rt]
    const f32x4 z4 = {0.f, 0.f, 0.f, 0.f};
    #pragma unroll
    for (int a = 0; a < 2; ++a)
        #pragma unroll
        for (int b = 0; b < 4; ++b) acc[a][b] = z4;

    const int srow = tid >> 4, sf4 = tid & 15;       // staging role: row, float4-lane
    const float* xgr = x + (size_t)(mb * 64 + srow) * KDIM;
    const unsigned short* wb0 = wb + ((size_t)(wave * 2) * 64 + lane) * 8;

    for (int h = 0; h < 2; ++h) {
        if (h) __syncthreads();            // readers of xs (half 0 inner loop) done
        // stage half h: 64 rows x 512 k, fp32 -> bf16, coalesced float4 loads
        #pragma unroll
        for (int seg = 0; seg < 8; ++seg) {
            int f4 = sf4 + seg * 16;       // 0..127
            float4 v = *(const float4*)(xgr + h * 512 + f4 * 4);
            uint2 pk;
            pk.x = pack2_bf16(v.x, v.y);
            pk.y = pack2_bf16(v.z, v.w);
            *(uint2*)&xs[srow * XSTR2 + f4 * 4] = pk;
        }
        __syncthreads();                   // stage visible to all
        #pragma unroll 4
        for (int ksl = 0; ksl < 16; ++ksl) {
            const int ks = h * 16 + ksl;
            bf16x8 bf[4], af[2];
            #pragma unroll
            for (int rt = 0; rt < 4; ++rt)
                bf[rt] = *(const bf16x8*)&xs[(rt * 16 + l16) * XSTR2 + ksl * 32 + quad * 8];
            const unsigned short* wbase = wb0 + (size_t)ks * 16384;
            af[0] = *(const bf16x8*)(wbase);
            af[1] = *(const bf16x8*)(wbase + 512);
            #pragma unroll
            for (int ct = 0; ct < 2; ++ct)
                #pragma unroll
                for (int rt = 0; rt < 4; ++rt)
                    acc[ct][rt] = __builtin_amdgcn_mfma_f32_16x16x32_bf16(af[ct], bf[rt], acc[ct][rt], 0, 0, 0);
        }
    }

    // two 32-row phases: epilogue(s->st, R0 layout) -> scan (R0 body) -> GEMM2 -> out
    #pragma unroll
    for (int p = 0; p < 2; ++p) {
        if (p) __syncthreads();            // gemm2 p=0 readers of st done
        #pragma unroll
        for (int rt2 = 0; rt2 < 2; ++rt2) {
            int r = rt2 * 16 + l16;        // phase-local row 0..31
            #pragma unroll
            for (int ct = 0; ct < 2; ++ct) {
                int colb = wave * 32 + ct * 16 + quad * 4;     // global node col 0..511
                f32x4 a = acc[ct][p * 2 + rt2];
                float s0[4];
                #pragma unroll
                for (int j = 0; j < 4; ++j) {
                    float u = a[j];
                    u = fminf(fmaxf(u, -0.5f), 0.5f);          // cubic(+-.5) = 1/0 exactly
                    s0[j] = u * (1.5f - 2.0f * u * u) + 0.5f;
                }
                uint2 pk;
                pk.x = pack2_bf16(s0[0], s0[1]);
                pk.y = pack2_bf16(s0[2], s0[3]);
                *(uint2*)&st[r * RSTR + (colb >> 6) * TSTR + (colb & 63)] = pk;
            }
        }
        __syncthreads();
        // scan: one (row, tree) per thread, in place s -> mu (R0's exact body)
        if (tid < 256) {
            int r = tid >> 3, t = tid & 7;
            unsigned short* base = &st[r * RSTR + t * TSTR];
            uint4 q[8];
            #pragma unroll
            for (int c = 0; c < 8; ++c) q[c] = *(const uint4*)(base + c * 8);
            float mu[32];
            mu[0] = 1.0f;
            int start = 0;
            #pragma unroll
            for (int lvl = 0; lvl < 5; ++lvl) {
                int width = 1 << lvl;
                #pragma unroll
                for (int j = width - 1; j >= 0; --j) {
                    float m = mu[j], s_ = gs_get(q, start + j);
                    mu[2 * j + 1] = m * (1.0f - s_);
                    mu[2 * j]     = m * s_;
                }
                start += width;
            }
            #pragma unroll
            for (int c = 0; c < 8; ++c) {
                unsigned pk2[4];
                #pragma unroll
                for (int e = 0; e < 4; ++e) {
                    int j = c * 4 + e;
                    float m = mu[j], s_ = gs_get(q, 31 + j);
                    pk2[e] = pack2_bf16(m * s_, m * (1.0f - s_));
                }
                uint4 v; v.x = pk2[0]; v.y = pk2[1]; v.z = pk2[2]; v.w = pk2[3];
                *(uint4*)(base + c * 8) = v;
            }
        }
        __syncthreads();
        // GEMM2: A = leaf (global fragment-linear, L2-hot), B = mu (st, R0 layout)
        {
            int rtile = wave & 1, obk = wave >> 1;
            int mr = rtile * 16 + l16;
            f32x4 a2 = z4;
            #pragma unroll
            for (int kq = 0; kq < 16; ++kq) {
                int c0 = kq * 32 + quad * 8;
                bf16x8 bmu = *(const bf16x8*)&st[mr * RSTR + (c0 >> 6) * TSTR + (c0 & 63)];
                bf16x8 alf = *(const bf16x8*)(lb + ((size_t)((kq * 8 + obk) * 64 + lane)) * 8);
                a2 = __builtin_amdgcn_mfma_f32_16x16x32_bf16(alf, bmu, a2, 0, 0, 0);
            }
            int rowg = mb * 64 + p * 32 + rtile * 16 + l16;
            int og = obk * 16 + quad * 4;
            *(f32x4*)(out + (size_t)rowg * 128 + og) = a2;
        }
    }
}

extern "C" void kernel_launch(void* const* d_in, const int* in_sizes, int n_in,
                              void* d_out, int out_size, void* d_ws, size_t ws_size,
                              hipStream_t stream) {
    const float* x  = (const float*)d_in[0];
    const float* nw = (const float*)d_in[1];
    const float* lw = (const float*)d_in[2];
    float* out = (float*)d_out;

    unsigned short* wb = (unsigned short*)d_ws;
    unsigned short* lb = (unsigned short*)((char*)d_ws + WS_LB_OFF);

    prep_w<<<2048, 256, 0, stream>>>(nw, wb);
    prep_l<<<256, 256, 0, stream>>>(lw, lb);
    fused<<<512, 1024, 0, stream>>>(x, wb, lb, out);
}

// Round 5
// 234.995 us; speedup vs baseline: 1.1664x; 1.0655x over previous
//
#include <hip/hip_runtime.h>
#include <hip/hip_bf16.h>
#include <stdint.h>

// B=32768, D=1024, T=8, O=128, DEPTH=6 -> 512 padded node cols (8 trees x 64)
#define KDIM 1024
#define XSTR2 520          // x LDS row stride (shorts): 1040 B = 260 dw == 4 mod 32 (bank-spread)
#define TSTR 72            // tree stride in st (shorts) — R0's proven layout
#define RSTR 584           // st row stride (shorts) = 8*TSTR + 8 pad; 292 dw == 4 mod 32 (kills 16-way row aliasing)

typedef __attribute__((ext_vector_type(4))) float f32x4;
typedef __attribute__((ext_vector_type(8))) short bf16x8;

// ws: wb [32 ks][32 cb][64 lane][8] bf16 = 1 MiB @0 ; lb [16 kq][8 obk][64 lane][8] bf16 @1 MiB
#define WS_LB_OFF ((size_t)1 << 20)

__device__ __forceinline__ unsigned short f2bf_rne(float f) {
    unsigned u = __float_as_uint(f);
    u = (u + 0x7fffu + ((u >> 16) & 1u)) >> 16;
    return (unsigned short)u;
}

__device__ __forceinline__ unsigned int pack2_bf16(float a, float b) {
    __hip_bfloat162 h = __float22bfloat162_rn(make_float2(a, b));
    union { __hip_bfloat162 h; unsigned int u; } cv;
    cv.h = h;
    return cv.u;   // a low 16, b high
}

__device__ __forceinline__ float gs_get(const uint4* q, int i) {
    uint4 v = q[i >> 3];
    int c = (i >> 1) & 3;
    unsigned w = (c == 0) ? v.x : (c == 1) ? v.y : (c == 2) ? v.z : v.w;
    return __uint_as_float((i & 1) ? (w & 0xffff0000u) : (w << 16));
}

// ---- prep: node weights -> bf16 fragment-linear: wb[((ks*32+cb)*64+lane)*8+e]
//      = W[k = ks*32 + (lane>>4)*8 + e][col = cb*16 + (lane&15)]   (proven R2/R4)
__global__ void prep_w(const float* __restrict__ nw, unsigned short* __restrict__ wb) {
    int idx = blockIdx.x * 256 + threadIdx.x;       // 524288 total
    int e    = idx & 7;
    int lane = (idx >> 3) & 63;
    int cb   = (idx >> 9) & 31;
    int ks   = idx >> 14;
    int col = cb * 16 + (lane & 15);
    int k   = ks * 32 + (lane >> 4) * 8 + e;
    int t = col >> 6, i = col & 63;
    float v = (i < 63) ? nw[(t * KDIM + k) * 63 + i] : 0.0f;
    wb[idx] = f2bf_rne(v);
}

// ---- prep: leaf weights -> bf16 fragment-linear: lb[((kq*8+obk)*64+lane)*8+e]
//      = L[c = kq*32 + (lane>>4)*8 + e][o = obk*16 + (lane&15)]    (proven R2/R4)
__global__ void prep_l(const float* __restrict__ lw, unsigned short* __restrict__ lb) {
    int idx = blockIdx.x * 256 + threadIdx.x;       // 65536 total
    int e    = idx & 7;
    int lane = (idx >> 3) & 63;
    int obk  = (idx >> 9) & 7;
    int kq   = idx >> 12;
    int o = obk * 16 + (lane & 15);
    int c = kq * 32 + (lane >> 4) * 8 + e;
    int t = c >> 6, l = c & 63;
    lb[idx] = f2bf_rne(lw[(t * 128 + o) * 64 + l]);
}

// ---- fused: block = 1024 thr (16 waves), tile 64 rows x 512 cols, acc[2][4].
// x staged to LDS bf16 in TWO 512-k halves (R4's proven barrier-stage-barrier,
// 3 barriers in GEMM1). W/leaf direct-global fragment-linear (L2-resident —
// x/out use NON-TEMPORAL accesses so they don't evict wb/lb from L2).
__launch_bounds__(1024, 4)
__global__ void fused(const float* __restrict__ x, const unsigned short* __restrict__ wb,
                      const unsigned short* __restrict__ lb, float* __restrict__ out) {
    __shared__ __align__(16) unsigned short xs[64 * XSTR2];   // 66,560 B
    __shared__ __align__(16) unsigned short st[32 * RSTR];    // 37,376 B

    const int tid  = threadIdx.x;
    const int wave = tid >> 6, lane = tid & 63;
    const int quad = lane >> 4, l16 = lane & 15;
    const int mb   = blockIdx.x;           // 512 blocks x 64 rows

    f32x4 acc[2][4];                       // [ct][rt]
    const f32x4 z4 = {0.f, 0.f, 0.f, 0.f};
    #pragma unroll
    for (int a = 0; a < 2; ++a)
        #pragma unroll
        for (int b = 0; b < 4; ++b) acc[a][b] = z4;

    const int srow = tid >> 4, sf4 = tid & 15;       // staging role: row, float4-lane
    const float* xgr = x + (size_t)(mb * 64 + srow) * KDIM;
    const unsigned short* wb0 = wb + ((size_t)(wave * 2) * 64 + lane) * 8;

    for (int h = 0; h < 2; ++h) {
        if (h) __syncthreads();            // readers of xs (half 0 inner loop) done
        // stage half h: 64 rows x 512 k, fp32 -> bf16, nt float4 loads (bypass-friendly)
        #pragma unroll
        for (int seg = 0; seg < 8; ++seg) {
            int f4 = sf4 + seg * 16;       // 0..127
            f32x4 v = __builtin_nontemporal_load((const f32x4*)(xgr + h * 512 + f4 * 4));
            uint2 pk;
            pk.x = pack2_bf16(v[0], v[1]);
            pk.y = pack2_bf16(v[2], v[3]);
            *(uint2*)&xs[srow * XSTR2 + f4 * 4] = pk;
        }
        __syncthreads();                   // stage visible to all
        #pragma unroll 4
        for (int ksl = 0; ksl < 16; ++ksl) {
            const int ks = h * 16 + ksl;
            bf16x8 bf[4], af[2];
            #pragma unroll
            for (int rt = 0; rt < 4; ++rt)
                bf[rt] = *(const bf16x8*)&xs[(rt * 16 + l16) * XSTR2 + ksl * 32 + quad * 8];
            const unsigned short* wbase = wb0 + (size_t)ks * 16384;
            af[0] = *(const bf16x8*)(wbase);
            af[1] = *(const bf16x8*)(wbase + 512);
            #pragma unroll
            for (int ct = 0; ct < 2; ++ct)
                #pragma unroll
                for (int rt = 0; rt < 4; ++rt)
                    acc[ct][rt] = __builtin_amdgcn_mfma_f32_16x16x32_bf16(af[ct], bf[rt], acc[ct][rt], 0, 0, 0);
        }
    }

    // two 32-row phases: epilogue(s->st) -> scan (R0 body) -> GEMM2 -> out
    #pragma unroll
    for (int p = 0; p < 2; ++p) {
        if (p) __syncthreads();            // gemm2 p=0 readers of st done
        #pragma unroll
        for (int rt2 = 0; rt2 < 2; ++rt2) {
            int r = rt2 * 16 + l16;        // phase-local row 0..31
            #pragma unroll
            for (int ct = 0; ct < 2; ++ct) {
                int colb = wave * 32 + ct * 16 + quad * 4;     // global node col 0..511
                f32x4 a = acc[ct][p * 2 + rt2];
                float s0[4];
                #pragma unroll
                for (int j = 0; j < 4; ++j) {
                    float u = a[j];
                    u = fminf(fmaxf(u, -0.5f), 0.5f);          // cubic(+-.5) = 1/0 exactly
                    s0[j] = u * (1.5f - 2.0f * u * u) + 0.5f;
                }
                uint2 pk;
                pk.x = pack2_bf16(s0[0], s0[1]);
                pk.y = pack2_bf16(s0[2], s0[3]);
                *(uint2*)&st[r * RSTR + (colb >> 6) * TSTR + (colb & 63)] = pk;
            }
        }
        __syncthreads();
        // scan: one (row, tree) per thread, in place s -> mu (R0's exact body)
        if (tid < 256) {
            int r = tid >> 3, t = tid & 7;
            unsigned short* base = &st[r * RSTR + t * TSTR];
            uint4 q[8];
            #pragma unroll
            for (int c = 0; c < 8; ++c) q[c] = *(const uint4*)(base + c * 8);
            float mu[32];
            mu[0] = 1.0f;
            int start = 0;
            #pragma unroll
            for (int lvl = 0; lvl < 5; ++lvl) {
                int width = 1 << lvl;
                #pragma unroll
                for (int j = width - 1; j >= 0; --j) {
                    float m = mu[j], s_ = gs_get(q, start + j);
                    mu[2 * j + 1] = m * (1.0f - s_);
                    mu[2 * j]     = m * s_;
                }
                start += width;
            }
            #pragma unroll
            for (int c = 0; c < 8; ++c) {
                unsigned pk2[4];
                #pragma unroll
                for (int e = 0; e < 4; ++e) {
                    int j = c * 4 + e;
                    float m = mu[j], s_ = gs_get(q, 31 + j);
                    pk2[e] = pack2_bf16(m * s_, m * (1.0f - s_));
                }
                uint4 v; v.x = pk2[0]; v.y = pk2[1]; v.z = pk2[2]; v.w = pk2[3];
                *(uint4*)(base + c * 8) = v;
            }
        }
        __syncthreads();
        // GEMM2: A = leaf (global fragment-linear, L2-hot), B = mu (st)
        {
            int rtile = wave & 1, obk = wave >> 1;
            int mr = rtile * 16 + l16;
            f32x4 a2 = z4;
            #pragma unroll
            for (int kq = 0; kq < 16; ++kq) {
                int c0 = kq * 32 + quad * 8;
                bf16x8 bmu = *(const bf16x8*)&st[mr * RSTR + (c0 >> 6) * TSTR + (c0 & 63)];
                bf16x8 alf = *(const bf16x8*)(lb + ((size_t)((kq * 8 + obk) * 64 + lane)) * 8);
                a2 = __builtin_amdgcn_mfma_f32_16x16x32_bf16(alf, bmu, a2, 0, 0, 0);
            }
            int rowg = mb * 64 + p * 32 + rtile * 16 + l16;
            int og = obk * 16 + quad * 4;
            __builtin_nontemporal_store(a2, (f32x4*)(out + (size_t)rowg * 128 + og));
        }
    }
}

extern "C" void kernel_launch(void* const* d_in, const int* in_sizes, int n_in,
                              void* d_out, int out_size, void* d_ws, size_t ws_size,
                              hipStream_t stream) {
    const float* x  = (const float*)d_in[0];
    const float* nw = (const float*)d_in[1];
    const float* lw = (const float*)d_in[2];
    float* out = (float*)d_out;

    unsigned short* wb = (unsigned short*)d_ws;
    unsigned short* lb = (unsigned short*)((char*)d_ws + WS_LB_OFF);

    prep_w<<<2048, 256, 0, stream>>>(nw, wb);
    prep_l<<<256, 256, 0, stream>>>(lw, lb);
    fused<<<512, 1024, 0, stream>>>(x, wb, lb, out);
}

// Round 7
// 234.620 us; speedup vs baseline: 1.1682x; 1.0016x over previous
//
#include <hip/hip_runtime.h>
#include <hip/hip_bf16.h>
#include <stdint.h>

// B=32768, D=1024, T=8, O=128, DEPTH=6 -> 512 padded node cols (8 trees x 64)
#define KDIM 1024
#define XSTR2 520          // x LDS row stride (shorts): 1040 B = 260 dw == 4 mod 32 (bank-spread)
#define TSTR 72            // tree stride in st (shorts) — R0's proven layout
#define RSTR 584           // st row stride (shorts) = 8*TSTR + 8 pad; 292 dw == 4 mod 32

typedef __attribute__((ext_vector_type(4))) float f32x4;
typedef __attribute__((ext_vector_type(8))) short bf16x8;

// ws: wb [32 ks][32 cb][64 lane][8] bf16 = 1 MiB @0 ; lb [16 kq][8 obk][64 lane][8] bf16 @1 MiB
#define WS_LB_OFF ((size_t)1 << 20)

__device__ __forceinline__ unsigned short f2bf_rne(float f) {
    unsigned u = __float_as_uint(f);
    u = (u + 0x7fffu + ((u >> 16) & 1u)) >> 16;
    return (unsigned short)u;
}

__device__ __forceinline__ unsigned int pack2_bf16(float a, float b) {
    __hip_bfloat162 h = __float22bfloat162_rn(make_float2(a, b));
    union { __hip_bfloat162 h; unsigned int u; } cv;
    cv.h = h;
    return cv.u;   // a low 16, b high
}

__device__ __forceinline__ float gs_get(const uint4* q, int i) {
    uint4 v = q[i >> 3];
    int c = (i >> 1) & 3;
    unsigned w = (c == 0) ? v.x : (c == 1) ? v.y : (c == 2) ? v.z : v.w;
    return __uint_as_float((i & 1) ? (w & 0xffff0000u) : (w << 16));
}

// ---- prep: node weights -> bf16 fragment-linear: wb[((ks*32+cb)*64+lane)*8+e]
//      = W[k = ks*32 + (lane>>4)*8 + e][col = cb*16 + (lane&15)]   (proven R2/R4/R5)
__global__ void prep_w(const float* __restrict__ nw, unsigned short* __restrict__ wb) {
    int idx = blockIdx.x * 256 + threadIdx.x;       // 524288 total
    int e    = idx & 7;
    int lane = (idx >> 3) & 63;
    int cb   = (idx >> 9) & 31;
    int ks   = idx >> 14;
    int col = cb * 16 + (lane & 15);
    int k   = ks * 32 + (lane >> 4) * 8 + e;
    int t = col >> 6, i = col & 63;
    float v = (i < 63) ? nw[(t * KDIM + k) * 63 + i] : 0.0f;
    wb[idx] = f2bf_rne(v);
}

// ---- prep: leaf weights -> bf16 fragment-linear: lb[((kq*8+obk)*64+lane)*8+e]
//      = L[c = kq*32 + (lane>>4)*8 + e][o = obk*16 + (lane&15)]    (proven R2/R4/R5)
__global__ void prep_l(const float* __restrict__ lw, unsigned short* __restrict__ lb) {
    int idx = blockIdx.x * 256 + threadIdx.x;       // 65536 total
    int e    = idx & 7;
    int lane = (idx >> 3) & 63;
    int obk  = (idx >> 9) & 7;
    int kq   = idx >> 12;
    int o = obk * 16 + (lane & 15);
    int c = kq * 32 + (lane >> 4) * 8 + e;
    int t = c >> 6, l = c & 63;
    lb[idx] = f2bf_rne(lw[(t * 128 + o) * 64 + l]);
}

// ---- fused: block = 1024 thr (16 waves), tile 64 rows x 512 cols, acc[2][4].
// x staged to LDS bf16 in TWO 512-k halves (proven barrier-stage-barrier).
// W/leaf direct-global fragment-linear; x/out non-temporal (keep wb/lb L2-hot).
// xs and st share one LDS union (temporally disjoint; unconditional barrier
// separates last xs read from first st write) -> 66,560 B -> 2 blocks/CU.
__launch_bounds__(1024, 4)
__global__ void fused(const float* __restrict__ x, const unsigned short* __restrict__ wb,
                      const unsigned short* __restrict__ lb, float* __restrict__ out) {
    __shared__ union __align__(16) {
        unsigned short xs[64 * XSTR2];     // 66,560 B (GEMM1 x tile)
        unsigned short st[32 * RSTR];      // 37,376 B (s/mu tile, after GEMM1)
    } sm;

    const int tid  = threadIdx.x;
    const int wave = tid >> 6, lane = tid & 63;
    const int quad = lane >> 4, l16 = lane & 15;
    const int mb   = blockIdx.x;           // 512 blocks x 64 rows

    f32x4 acc[2][4];                       // [ct][rt]
    const f32x4 z4 = {0.f, 0.f, 0.f, 0.f};
    #pragma unroll
    for (int a = 0; a < 2; ++a)
        #pragma unroll
        for (int b = 0; b < 4; ++b) acc[a][b] = z4;

    const int srow = tid >> 4, sf4 = tid & 15;       // staging role: row, float4-lane
    const float* xgr = x + (size_t)(mb * 64 + srow) * KDIM;
    const unsigned short* wb0 = wb + ((size_t)(wave * 2) * 64 + lane) * 8;

    for (int h = 0; h < 2; ++h) {
        if (h) __syncthreads();            // readers of xs (half 0 inner loop) done
        // stage half h: 64 rows x 512 k, fp32 -> bf16, nt float4 loads
        #pragma unroll
        for (int seg = 0; seg < 8; ++seg) {
            int f4 = sf4 + seg * 16;       // 0..127
            f32x4 v = __builtin_nontemporal_load((const f32x4*)(xgr + h * 512 + f4 * 4));
            uint2 pk;
            pk.x = pack2_bf16(v[0], v[1]);
            pk.y = pack2_bf16(v[2], v[3]);
            *(uint2*)&sm.xs[srow * XSTR2 + f4 * 4] = pk;
        }
        __syncthreads();                   // stage visible to all
        #pragma unroll 4
        for (int ksl = 0; ksl < 16; ++ksl) {
            const int ks = h * 16 + ksl;
            bf16x8 bf[4], af[2];
            #pragma unroll
            for (int rt = 0; rt < 4; ++rt)
                bf[rt] = *(const bf16x8*)&sm.xs[(rt * 16 + l16) * XSTR2 + ksl * 32 + quad * 8];
            const unsigned short* wbase = wb0 + (size_t)ks * 16384;
            af[0] = *(const bf16x8*)(wbase);
            af[1] = *(const bf16x8*)(wbase + 512);
            #pragma unroll
            for (int ct = 0; ct < 2; ++ct)
                #pragma unroll
                for (int rt = 0; rt < 4; ++rt)
                    acc[ct][rt] = __builtin_amdgcn_mfma_f32_16x16x32_bf16(af[ct], bf[rt], acc[ct][rt], 0, 0, 0);
        }
    }

    // two 32-row phases: epilogue(s->st) -> scan (R0 body) -> GEMM2 -> out
    #pragma unroll
    for (int p = 0; p < 2; ++p) {
        __syncthreads();   // p=0: ALL waves done reading xs (union safety); p=1: gemm2 readers done
        #pragma unroll
        for (int rt2 = 0; rt2 < 2; ++rt2) {
            int r = rt2 * 16 + l16;        // phase-local row 0..31
            #pragma unroll
            for (int ct = 0; ct < 2; ++ct) {
                int colb = wave * 32 + ct * 16 + quad * 4;     // global node col 0..511
                f32x4 a = acc[ct][p * 2 + rt2];
                float s0[4];
                #pragma unroll
                for (int j = 0; j < 4; ++j) {
                    float u = a[j];
                    u = fminf(fmaxf(u, -0.5f), 0.5f);          // cubic(+-.5) = 1/0 exactly
                    s0[j] = u * (1.5f - 2.0f * u * u) + 0.5f;
                }
                uint2 pk;
                pk.x = pack2_bf16(s0[0], s0[1]);
                pk.y = pack2_bf16(s0[2], s0[3]);
                *(uint2*)&sm.st[r * RSTR + (colb >> 6) * TSTR + (colb & 63)] = pk;
            }
        }
        __syncthreads();
        // scan: one (row, tree) per thread, in place s -> mu (R0's exact body)
        if (tid < 256) {
            int r = tid >> 3, t = tid & 7;
            unsigned short* base = &sm.st[r * RSTR + t * TSTR];
            uint4 q[8];
            #pragma unroll
            for (int c = 0; c < 8; ++c) q[c] = *(const uint4*)(base + c * 8);
            float mu[32];
            mu[0] = 1.0f;
            int start = 0;
            #pragma unroll
            for (int lvl = 0; lvl < 5; ++lvl) {
                int width = 1 << lvl;
                #pragma unroll
                for (int j = width - 1; j >= 0; --j) {
                    float m = mu[j], s_ = gs_get(q, start + j);
                    mu[2 * j + 1] = m * (1.0f - s_);
                    mu[2 * j]     = m * s_;
                }
                start += width;
            }
            #pragma unroll
            for (int c = 0; c < 8; ++c) {
                unsigned pk2[4];
                #pragma unroll
                for (int e = 0; e < 4; ++e) {
                    int j = c * 4 + e;
                    float m = mu[j], s_ = gs_get(q, 31 + j);
                    pk2[e] = pack2_bf16(m * s_, m * (1.0f - s_));
                }
                uint4 v; v.x = pk2[0]; v.y = pk2[1]; v.z = pk2[2]; v.w = pk2[3];
                *(uint4*)(base + c * 8) = v;
            }
        }
        __syncthreads();
        // GEMM2: A = leaf (global fragment-linear, L2-hot), B = mu (st)
        {
            int rtile = wave & 1, obk = wave >> 1;
            int mr = rtile * 16 + l16;
            f32x4 a2 = z4;
            #pragma unroll
            for (int kq = 0; kq < 16; ++kq) {
                int c0 = kq * 32 + quad * 8;
                bf16x8 bmu = *(const bf16x8*)&sm.st[mr * RSTR + (c0 >> 6) * TSTR + (c0 & 63)];
                bf16x8 alf = *(const bf16x8*)(lb + ((size_t)((kq * 8 + obk) * 64 + lane)) * 8);
                a2 = __builtin_amdgcn_mfma_f32_16x16x32_bf16(alf, bmu, a2, 0, 0, 0);
            }
            int rowg = mb * 64 + p * 32 + rtile * 16 + l16;
            int og = obk * 16 + quad * 4;
            __builtin_nontemporal_store(a2, (f32x4*)(out + (size_t)rowg * 128 + og));
        }
    }
}

extern "C" void kernel_launch(void* const* d_in, const int* in_sizes, int n_in,
                              void* d_out, int out_size, void* d_ws, size_t ws_size,
                              hipStream_t stream) {
    const float* x  = (const float*)d_in[0];
    const float* nw = (const float*)d_in[1];
    const float* lw = (const float*)d_in[2];
    float* out = (float*)d_out;

    unsigned short* wb = (unsigned short*)d_ws;
    unsigned short* lb = (unsigned short*)((char*)d_ws + WS_LB_OFF);

    prep_w<<<2048, 256, 0, stream>>>(nw, wb);
    prep_l<<<256, 256, 0, stream>>>(lw, lb);
    fused<<<512, 1024, 0, stream>>>(x, wb, lb, out);
}

// Round 8
// 231.314 us; speedup vs baseline: 1.1849x; 1.0143x over previous
//
#include <hip/hip_runtime.h>
#include <hip/hip_bf16.h>
#include <stdint.h>

// B=32768, D=1024, T=8, O=128, DEPTH=6 -> 512 padded node cols (8 trees x 64)
#define KDIM 1024
#define XSTR2 520          // x LDS row stride (shorts): 1040 B = 260 dw == 4 mod 32 (bank-spread)
#define TSTR 72            // tree stride in st (shorts) — proven layout
#define RSTR 584           // st row stride (shorts) = 8*TSTR + 8 pad; 292 dw == 4 mod 32

typedef __attribute__((ext_vector_type(4))) float f32x4;
typedef __attribute__((ext_vector_type(8))) short bf16x8;

// ws: wb [32 ks][32 cb][64 lane][8] bf16 = 1 MiB @0 ; lb [16 kq][8 obk][64 lane][8] bf16 @1 MiB
#define WS_LB_OFF ((size_t)1 << 20)

__device__ __forceinline__ unsigned short f2bf_rne(float f) {
    unsigned u = __float_as_uint(f);
    u = (u + 0x7fffu + ((u >> 16) & 1u)) >> 16;
    return (unsigned short)u;
}

__device__ __forceinline__ unsigned int pack2_bf16(float a, float b) {
    __hip_bfloat162 h = __float22bfloat162_rn(make_float2(a, b));
    union { __hip_bfloat162 h; unsigned int u; } cv;
    cv.h = h;
    return cv.u;   // a low 16, b high
}

__device__ __forceinline__ float gs_get(const uint4* q, int i) {
    uint4 v = q[i >> 3];
    int c = (i >> 1) & 3;
    unsigned w = (c == 0) ? v.x : (c == 1) ? v.y : (c == 2) ? v.z : v.w;
    return __uint_as_float((i & 1) ? (w & 0xffff0000u) : (w << 16));
}

// ---- merged prep: blocks [0,2048) = node weights, [2048,2304) = leaf weights.
// wb[((ks*32+cb)*64+lane)*8+e] = W[k = ks*32+(lane>>4)*8+e][col = cb*16+(lane&15)]
// lb[((kq*8+obk)*64+lane)*8+e] = L[c = kq*32+(lane>>4)*8+e][o = obk*16+(lane&15)]
__global__ void prep(const float* __restrict__ nw, const float* __restrict__ lw,
                     unsigned short* __restrict__ wb, unsigned short* __restrict__ lb) {
    int b = blockIdx.x;
    if (b < 2048) {
        int idx = b * 256 + threadIdx.x;            // 524288 total
        int e    = idx & 7;
        int lane = (idx >> 3) & 63;
        int cb   = (idx >> 9) & 31;
        int ks   = idx >> 14;
        int col = cb * 16 + (lane & 15);
        int k   = ks * 32 + (lane >> 4) * 8 + e;
        int t = col >> 6, i = col & 63;
        float v = (i < 63) ? nw[(t * KDIM + k) * 63 + i] : 0.0f;
        wb[idx] = f2bf_rne(v);
    } else {
        int idx = (b - 2048) * 256 + threadIdx.x;   // 65536 total
        int e    = idx & 7;
        int lane = (idx >> 3) & 63;
        int obk  = (idx >> 9) & 7;
        int kq   = idx >> 12;
        int o = obk * 16 + (lane & 15);
        int c = kq * 32 + (lane >> 4) * 8 + e;
        int t = c >> 6, l = c & 63;
        lb[idx] = f2bf_rne(lw[(t * 128 + o) * 64 + l]);
    }
}

// compute one 512-k half (16 x K=32 sub-steps) from an xs buffer
__device__ __forceinline__ void compute_half(const unsigned short* __restrict__ xb,
                                             const unsigned short* __restrict__ wb0,
                                             int ksbase, int l16, int quad,
                                             f32x4 (&acc)[2][4]) {
    #pragma unroll 4
    for (int ksl = 0; ksl < 16; ++ksl) {
        const int ks = ksbase + ksl;
        bf16x8 bf[4], af[2];
        #pragma unroll
        for (int rt = 0; rt < 4; ++rt)
            bf[rt] = *(const bf16x8*)&xb[(rt * 16 + l16) * XSTR2 + ksl * 32 + quad * 8];
        const unsigned short* wbase = wb0 + (size_t)ks * 16384;
        af[0] = *(const bf16x8*)(wbase);
        af[1] = *(const bf16x8*)(wbase + 512);
        #pragma unroll
        for (int ct = 0; ct < 2; ++ct)
            #pragma unroll
            for (int rt = 0; rt < 4; ++rt)
                acc[ct][rt] = __builtin_amdgcn_mfma_f32_16x16x32_bf16(af[ct], bf[rt], acc[ct][rt], 0, 0, 0);
    }
}

// ---- fused: block = 1024 thr (16 waves), tile 64 rows x 512 cols, acc[2][4].
// GEMM1: xs double-buffered halves; half-1 loaded into REGISTERS during
// compute of half-0 (T14 issue-early/write-late), packed+written after, one
// plain barrier, then computed. W direct-global fragment-linear (L2-hot);
// x/out non-temporal. Tail: single 64-row pass (epilogue -> scan -> GEMM2).
__launch_bounds__(1024, 4)
__global__ void fused(const float* __restrict__ x, const unsigned short* __restrict__ wb,
                      const unsigned short* __restrict__ lb, float* __restrict__ out) {
    __shared__ union __align__(16) {
        unsigned short xs[2][64 * XSTR2];  // 2 x 66,560 B (GEMM1 x halves)
        unsigned short st[64 * RSTR];      // 74,752 B (s/mu tile, after GEMM1)
    } sm;

    const int tid  = threadIdx.x;
    const int wave = tid >> 6, lane = tid & 63;
    const int quad = lane >> 4, l16 = lane & 15;
    const int mb   = blockIdx.x;           // 512 blocks x 64 rows

    f32x4 acc[2][4];                       // [ct][rt]
    const f32x4 z4 = {0.f, 0.f, 0.f, 0.f};
    #pragma unroll
    for (int a = 0; a < 2; ++a)
        #pragma unroll
        for (int b = 0; b < 4; ++b) acc[a][b] = z4;

    const int srow = tid >> 4, sf4 = tid & 15;       // staging role: row, float4-lane
    const float* xgr = x + (size_t)(mb * 64 + srow) * KDIM;
    const unsigned short* wb0 = wb + ((size_t)(wave * 2) * 64 + lane) * 8;

    // stage half 0: nt load -> pack -> ds_write
    #pragma unroll
    for (int seg = 0; seg < 8; ++seg) {
        int f4 = sf4 + seg * 16;           // 0..127
        f32x4 v = __builtin_nontemporal_load((const f32x4*)(xgr + f4 * 4));
        uint2 pk;
        pk.x = pack2_bf16(v[0], v[1]);
        pk.y = pack2_bf16(v[2], v[3]);
        *(uint2*)&sm.xs[0][srow * XSTR2 + f4 * 4] = pk;
    }
    __syncthreads();                       // half 0 visible

    // prefetch half 1 into registers (issued up-front; lands under compute_half 0)
    f32x4 pre[8];
    #pragma unroll
    for (int seg = 0; seg < 8; ++seg) {
        int f4 = sf4 + seg * 16;
        pre[seg] = __builtin_nontemporal_load((const f32x4*)(xgr + 512 + f4 * 4));
    }

    compute_half(sm.xs[0], wb0, 0, l16, quad, acc);

    // write half 1 (other buffer -- no conflict with half-0 readers)
    #pragma unroll
    for (int seg = 0; seg < 8; ++seg) {
        int f4 = sf4 + seg * 16;
        uint2 pk;
        pk.x = pack2_bf16(pre[seg][0], pre[seg][1]);
        pk.y = pack2_bf16(pre[seg][2], pre[seg][3]);
        *(uint2*)&sm.xs[1][srow * XSTR2 + f4 * 4] = pk;
    }
    __syncthreads();                       // half 1 visible; half-0 reads done

    compute_half(sm.xs[1], wb0, 16, l16, quad, acc);

    __syncthreads();                       // all xs reads done -> st may alias
    // epilogue: smooth_step, all 64 rows -> st (tree-strided layout)
    #pragma unroll
    for (int rt = 0; rt < 4; ++rt) {
        int r = rt * 16 + l16;             // row 0..63
        #pragma unroll
        for (int ct = 0; ct < 2; ++ct) {
            int colb = wave * 32 + ct * 16 + quad * 4;     // node col 0..511
            f32x4 a = acc[ct][rt];
            float s0[4];
            #pragma unroll
            for (int j = 0; j < 4; ++j) {
                float u = a[j];
                u = fminf(fmaxf(u, -0.5f), 0.5f);          // cubic(+-.5) = 1/0 exactly
                s0[j] = u * (1.5f - 2.0f * u * u) + 0.5f;
            }
            uint2 pk;
            pk.x = pack2_bf16(s0[0], s0[1]);
            pk.y = pack2_bf16(s0[2], s0[3]);
            *(uint2*)&sm.st[r * RSTR + (colb >> 6) * TSTR + (colb & 63)] = pk;
        }
    }
    __syncthreads();
    // scan: one (row, tree) per thread, 512 tasks, in place s -> mu
    if (tid < 512) {
        int r = tid >> 3, t = tid & 7;
        unsigned short* base = &sm.st[r * RSTR + t * TSTR];
        uint4 q[8];
        #pragma unroll
        for (int c = 0; c < 8; ++c) q[c] = *(const uint4*)(base + c * 8);
        float mu[32];
        mu[0] = 1.0f;
        int start = 0;
        #pragma unroll
        for (int lvl = 0; lvl < 5; ++lvl) {
            int width = 1 << lvl;
            #pragma unroll
            for (int j = width - 1; j >= 0; --j) {
                float m = mu[j], s_ = gs_get(q, start + j);
                mu[2 * j + 1] = m * (1.0f - s_);
                mu[2 * j]     = m * s_;
            }
            start += width;
        }
        #pragma unroll
        for (int c = 0; c < 8; ++c) {
            unsigned pk2[4];
            #pragma unroll
            for (int e = 0; e < 4; ++e) {
                int j = c * 4 + e;
                float m = mu[j], s_ = gs_get(q, 31 + j);
                pk2[e] = pack2_bf16(m * s_, m * (1.0f - s_));
            }
            uint4 v; v.x = pk2[0]; v.y = pk2[1]; v.z = pk2[2]; v.w = pk2[3];
            *(uint4*)(base + c * 8) = v;
        }
    }
    __syncthreads();
    // GEMM2: A = leaf (global fragment-linear, L2-hot), B = mu (st)
    // wave -> (rtile = wave&3, obk pair = wave>>2); 2 outputs per wave
    {
        int rtile = wave & 3, obk2 = wave >> 2;
        int mr = rtile * 16 + l16;         // row 0..63
        f32x4 a2[2];
        a2[0] = z4; a2[1] = z4;
        #pragma unroll
        for (int kq = 0; kq < 16; ++kq) {
            int c0 = kq * 32 + quad * 8;
            bf16x8 bmu = *(const bf16x8*)&sm.st[mr * RSTR + (c0 >> 6) * TSTR + (c0 & 63)];
            #pragma unroll
            for (int i = 0; i < 2; ++i) {
                int obk = obk2 * 2 + i;
                bf16x8 alf = *(const bf16x8*)(lb + ((size_t)((kq * 8 + obk) * 64 + lane)) * 8);
                a2[i] = __builtin_amdgcn_mfma_f32_16x16x32_bf16(alf, bmu, a2[i], 0, 0, 0);
            }
        }
        int rowg = mb * 64 + rtile * 16 + l16;
        #pragma unroll
        for (int i = 0; i < 2; ++i) {
            int og = (obk2 * 2 + i) * 16 + quad * 4;
            __builtin_nontemporal_store(a2[i], (f32x4*)(out + (size_t)rowg * 128 + og));
        }
    }
}

extern "C" void kernel_launch(void* const* d_in, const int* in_sizes, int n_in,
                              void* d_out, int out_size, void* d_ws, size_t ws_size,
                              hipStream_t stream) {
    const float* x  = (const float*)d_in[0];
    const float* nw = (const float*)d_in[1];
    const float* lw = (const float*)d_in[2];
    float* out = (float*)d_out;

    unsigned short* wb = (unsigned short*)d_ws;
    unsigned short* lb = (unsigned short*)((char*)d_ws + WS_LB_OFF);

    prep<<<2304, 256, 0, stream>>>(nw, lw, wb, lb);
    fused<<<512, 1024, 0, stream>>>(x, wb, lb, out);
}